// Round 12
// baseline (534.246 us; speedup 1.0000x reference)
//
#include <hip/hip_runtime.h>
#include <cstdint>
#include <cstddef>

// ---------------------------------------------------------------------------
// GCN forward:  softmax( (A_hat relu(A_hat (X W1 + b1) W2)) Wl + bl )
// conv1 reordered: aggregate features (F=512) first, GEMM1 epilogue adds
// rowsum*b1. conv2: project (8192->4096) then aggregate.
// GEMM (R12): 128x128 tile, BK=64, 4 waves (2Mx2N, 64x64 wave tiles),
// double-buffered LDS = 64 KB  =>  TWO independent blocks per CU. All five
// 256^2 schedule variants plateaued at MfmaUtil 47% because 128KB LDS left
// ONE block/CU: every s_barrier idled the whole CU (LDS service and MFMA
// added, ~4900 cyc/K-tile = sum of pipes). Two async barrier domains let
// one block's MFMA phase cover the other's LDS/stage phase (m114/m103
// mechanism). Keeps: T2 XOR swizzle both sides (0 conflicts since R4),
// counted vmcnt(8), R7 compiler-scheduled 2-barrier body, stage-after-
// lgkm-drain region safety, bijective XCD swizzle.
// agg2: 512-col stripes pinned to XCDs via bid%8 -> gather from L2.
// Head: split-K MFMA head-GEMM + reduce/softmax (R9).
// ---------------------------------------------------------------------------

using bf8   = __attribute__((ext_vector_type(8))) short;   // 8 bf16 (4 VGPR)
using s4    = __attribute__((ext_vector_type(4))) short;
using f32x4 = __attribute__((ext_vector_type(4))) float;

static __device__ __forceinline__ unsigned short f2bf(float f) {
    union { float f; uint32_t u; } v; v.f = f;
    uint32_t r = (v.u + 0x7FFFu + ((v.u >> 16) & 1u)) >> 16;   // RNE
    return (unsigned short)r;
}
static __device__ __forceinline__ float bf2f(unsigned short b) {
    union { uint32_t u; float f; } v; v.u = ((uint32_t)b) << 16;
    return v.f;
}

static __device__ __forceinline__ void gload16(const short* g, short* l) {
    __builtin_amdgcn_global_load_lds(
        (const __attribute__((address_space(1))) unsigned int*)g,
        (__attribute__((address_space(3))) unsigned int*)l,
        16, 0, 0);
}

// ---------------- prep kernels ----------------

__global__ void k_zero(float* a, float* b, int* c, int n) {
    int i = blockIdx.x * blockDim.x + threadIdx.x;
    if (i < n) { a[i] = 0.f; b[i] = 0.f; c[i] = 0; }
}

__global__ void k_count(const int* __restrict__ src, const int* __restrict__ dst,
                        float* deg_out, float* deg_in, int E) {
    int e = blockIdx.x * blockDim.x + threadIdx.x;
    if (e < E) {
        atomicAdd(&deg_out[src[e]], 1.f);
        atomicAdd(&deg_in[dst[e]], 1.f);
    }
}

__global__ void k_inv(const float* deg_out, const float* deg_in,
                      float* inv_out, float* inv_in, int n) {
    int i = blockIdx.x * blockDim.x + threadIdx.x;
    if (i < n) {
        inv_out[i] = rsqrtf(fmaxf(deg_out[i], 1.f));
        inv_in[i]  = rsqrtf(fmaxf(deg_in[i], 1.f));
    }
}

__global__ void k_scan(const float* __restrict__ deg_in, int* __restrict__ row_off) {
    __shared__ int part[1024];
    const int t = threadIdx.x;
    int v0 = (int)deg_in[t*4+0], v1 = (int)deg_in[t*4+1],
        v2 = (int)deg_in[t*4+2], v3 = (int)deg_in[t*4+3];
    part[t] = v0 + v1 + v2 + v3;
    __syncthreads();
    for (int off = 1; off < 1024; off <<= 1) {
        int x = (t >= off) ? part[t - off] : 0;
        __syncthreads();
        part[t] += x;
        __syncthreads();
    }
    int run = (t == 0) ? 0 : part[t-1];
    row_off[t*4+0] = run; run += v0;
    row_off[t*4+1] = run; run += v1;
    row_off[t*4+2] = run; run += v2;
    row_off[t*4+3] = run; run += v3;
    if (t == 1023) row_off[4096] = run;
}

__global__ void k_fill(const int* __restrict__ src, const int* __restrict__ dst,
                       const int* __restrict__ row_off, int* cursor,
                       int* __restrict__ esrc, int E) {
    int e = blockIdx.x * blockDim.x + threadIdx.x;
    if (e < E) {
        int d = dst[e];
        int p = atomicAdd(&cursor[d], 1);
        esrc[row_off[d] + p] = src[e];
    }
}

__global__ void k_rowsum(const int* __restrict__ row_off, const int* __restrict__ esrc,
                         const float* __restrict__ inv_out, const float* __restrict__ inv_in,
                         float* __restrict__ rowsum) {
    const int node = blockIdx.x, lane = threadIdx.x;
    const int beg = row_off[node], end = row_off[node + 1];
    float s = 0.f;
    for (int p = beg + lane; p < end; p += 64) s += inv_out[esrc[p]];
    #pragma unroll
    for (int off = 32; off; off >>= 1) s += __shfl_down(s, off, 64);
    if (lane == 0) rowsum[node] = s * inv_in[node];
}

__global__ void k_cvt_scale(const float* __restrict__ in, const float* __restrict__ sc,
                            short* __restrict__ out, int n4, int f4) {
    int i = blockIdx.x * blockDim.x + threadIdx.x;
    if (i < n4) {
        const float s = sc[i / f4];
        float4 v = reinterpret_cast<const float4*>(in)[i];
        s4 o;
        o[0] = (short)f2bf(v.x * s); o[1] = (short)f2bf(v.y * s);
        o[2] = (short)f2bf(v.z * s); o[3] = (short)f2bf(v.w * s);
        reinterpret_cast<s4*>(out)[i] = o;
    }
}

// fp32 [R][C] -> bf16 [C][R]; 64x64 tiles, 256 threads.
__global__ __launch_bounds__(256)
void k_tr3(const float* __restrict__ in, short* __restrict__ out, int R, int C) {
    __shared__ float tile[64][65];
    const int bc = blockIdx.x * 64, br = blockIdx.y * 64;
    const int t = threadIdx.x;
    const int rr = t >> 4, cq = (t & 15) * 4;
    #pragma unroll
    for (int p = 0; p < 4; ++p) {
        const int r = rr + p * 16;
        float4 v = *reinterpret_cast<const float4*>(&in[(size_t)(br + r) * C + bc + cq]);
        tile[r][cq + 0] = v.x; tile[r][cq + 1] = v.y;
        tile[r][cq + 2] = v.z; tile[r][cq + 3] = v.w;
    }
    __syncthreads();
    const int cc = t >> 4, rq = (t & 15) * 4;
    #pragma unroll
    for (int p = 0; p < 4; ++p) {
        const int c = cc + p * 16;
        s4 o;
        o[0] = (short)f2bf(tile[rq + 0][c]);
        o[1] = (short)f2bf(tile[rq + 1][c]);
        o[2] = (short)f2bf(tile[rq + 2][c]);
        o[3] = (short)f2bf(tile[rq + 3][c]);
        *reinterpret_cast<s4*>(&out[(size_t)(bc + c) * R + br + rq]) = o;
    }
}

// ---------------- bf16 MFMA GEMM, 128x128 2-blocks/CU pipeline ----------------
// C[M][N] = A[M][K] * Bt^T; A row-major, Bt = B^T row-major [N][K], all bf16.
// EPI==1: out = acc + rs[row]*bias[col]; EPI==2: out = acc * rs[row].
// Tile 128x128, BK=64. 4 waves = 2M x 2N, wave tile 64x64 (4x4 frags,
// 32 MFMA/K-tile/wave). LDS: 2 buf x (A[128][64]+B[128][64]) = 64 KB =>
// 2 blocks/CU (the overlap mechanism). Staging: 8 units/tile of 4 KB
// (32 rows x 8 chunks of 16B = 256 thr x 16B); linear LDS dest, source
// chunk pre-swizzled cs = cq ^ (row&7); ds_read same XOR (rule #21).
// Loop (R7 body): vmcnt(8) [tile t landed, t+1 in flight]; barrier;
// {16 ds_read + 32 MFMA, compiler-scheduled}; lgkmcnt(0); barrier;
// stage t+2 into buf[t&1]. Drain-0 only at the last tile.
// Requires nt >= 2 and M%128==N%128==K%64==0; grid nwg%8==0 (XCD swizzle).
template<int EPI>
__global__ __launch_bounds__(256, 2)
void gemm8p(const short* __restrict__ A, const short* __restrict__ Bt,
            short* __restrict__ C,
            const float* __restrict__ bias, const float* __restrict__ rs,
            int M, int N, int K)
{
    constexpr int USZ  = 2048;            // shorts per 32-row x 64-short unit (4 KB)
    constexpr int BOFF = 4 * USZ;         // B region offset within buffer (8192)
    constexpr int BUF  = 8 * USZ;         // shorts per buffer (16384 = 32 KB)
    __shared__ __align__(16) short lds[2 * BUF];   // 64 KB
    const int tid  = threadIdx.x;
    const int wid  = tid >> 6, lane = tid & 63;
    const int wm   = wid >> 1;            // 0..1  (M wave index)
    const int wn   = wid & 1;             // 0..1  (N wave index)
    const int fr   = lane & 15;
    const int kq   = lane >> 4;           // 0..3
    const int nt   = K >> 6;

    // bijective XCD-chunk swizzle (nwg % 8 == 0)
    const int gx  = gridDim.x;
    const int nwg = gx * gridDim.y;
    int bid = blockIdx.y * gx + blockIdx.x;
    bid = (bid & 7) * (nwg >> 3) + (bid >> 3);
    const int tm = (bid / gx) * 128;
    const int tn = (bid % gx) * 128;

    // ---- staging addressing (per thread: 1 gload16 per 4 KB unit) ----
    const int srow = tid >> 3;            // 0..31 row within unit
    const int scq  = tid & 7;             // linear 16B-chunk within row
    const int scs  = scq ^ (srow & 7);    // pre-swizzled source chunk
    const short* gA = A  + (size_t)(tm + srow) * K + scs * 8;
    const short* gB = Bt + (size_t)(tn + srow) * K + scs * 8;
    short* const ldst = lds + tid * 8;    // + bufoff + unit*USZ (shorts)

    // ---- fragment read offsets (shorts, lane-constant) ----
    const int cx0 = (0 * 4 + kq) ^ (fr & 7);
    const int cx1 = (1 * 4 + kq) ^ (fr & 7);
    int aoff[4][2], boff[4][2];
    #pragma unroll
    for (int mi = 0; mi < 4; ++mi) {
        const int r = wm * 64 + mi * 16 + fr;
        aoff[mi][0] = r * 64 + cx0 * 8;
        aoff[mi][1] = r * 64 + cx1 * 8;
    }
    #pragma unroll
    for (int n = 0; n < 4; ++n) {
        const int r = wn * 64 + n * 16 + fr;
        boff[n][0] = BOFF + r * 64 + cx0 * 8;
        boff[n][1] = BOFF + r * 64 + cx1 * 8;
    }

    f32x4 acc[4][4];
    #pragma unroll
    for (int mi = 0; mi < 4; ++mi)
        #pragma unroll
        for (int n = 0; n < 4; ++n)
            acc[mi][n] = (f32x4){0.f, 0.f, 0.f, 0.f};

    // ---- prologue: stage tile 0 -> buf0, tile 1 -> buf1 (16 loads in flight) ----
    #pragma unroll
    for (int u = 0; u < 4; ++u) gload16(gA + (size_t)u * 32 * K, ldst + u * USZ);
    #pragma unroll
    for (int v = 0; v < 4; ++v) gload16(gB + (size_t)v * 32 * K, ldst + BOFF + v * USZ);
    #pragma unroll
    for (int u = 0; u < 4; ++u) gload16(gA + (size_t)u * 32 * K + 64, ldst + BUF + u * USZ);
    #pragma unroll
    for (int v = 0; v < 4; ++v) gload16(gB + (size_t)v * 32 * K + 64, ldst + BUF + BOFF + v * USZ);

    for (int t = 0; t < nt; ++t) {
        const int cc = (t & 1) * BUF;     // compute buffer == stage target for t+2

        // tile t's loads have landed (counted: t+1's 8 stay in flight)
        if (t + 1 < nt) { asm volatile("s_waitcnt vmcnt(8)" ::: "memory"); }
        else            { asm volatile("s_waitcnt vmcnt(0)" ::: "memory"); }
        __builtin_amdgcn_sched_barrier(0);
        __builtin_amdgcn_s_barrier();

        // ---- tile body: compiler-scheduled reads + MFMAs (no pins) ----
        #pragma unroll
        for (int s = 0; s < 2; ++s) {
            bf8 b[4], a[4];
            #pragma unroll
            for (int n = 0; n < 4; ++n)
                b[n] = *reinterpret_cast<const bf8*>(lds + cc + boff[n][s]);
            #pragma unroll
            for (int mi = 0; mi < 4; ++mi)
                a[mi] = *reinterpret_cast<const bf8*>(lds + cc + aoff[mi][s]);
            #pragma unroll
            for (int mi = 0; mi < 4; ++mi)
                #pragma unroll
                for (int n = 0; n < 4; ++n)
                    acc[mi][n] = __builtin_amdgcn_mfma_f32_16x16x32_bf16(a[mi], b[n], acc[mi][n], 0, 0, 0);
        }

        // all my reads of buf[t&1] done; join workgroup; then overwrite it
        asm volatile("s_waitcnt lgkmcnt(0)" ::: "memory");
        __builtin_amdgcn_sched_barrier(0);
        __builtin_amdgcn_s_barrier();
        if (t + 2 < nt) {
            const size_t kf = (size_t)(t + 2) * 64;
            #pragma unroll
            for (int u = 0; u < 4; ++u)
                gload16(gA + (size_t)u * 32 * K + kf, ldst + cc + u * USZ);
            #pragma unroll
            for (int v = 0; v < 4; ++v)
                gload16(gB + (size_t)v * 32 * K + kf, ldst + cc + BOFF + v * USZ);
        }
    }

    // ---- epilogue: C/D layout col = lane&15, row = (lane>>4)*4 + reg ----
    const int rb = kq * 4;
    #pragma unroll
    for (int mi = 0; mi < 4; ++mi) {
        #pragma unroll
        for (int n = 0; n < 4; ++n) {
            const int col = tn + wn * 64 + n * 16 + fr;
            const float bcol = (EPI == 1) ? bias[col] : 0.f;
            #pragma unroll
            for (int j = 0; j < 4; ++j) {
                const int row = tm + wm * 64 + mi * 16 + rb + j;
                float v = acc[mi][n][j];
                if (EPI == 1) v += rs[row] * bcol;
                else          v *= rs[row];
                C[(size_t)row * N + col] = (short)f2bf(v);
            }
        }
    }
}

// ---------------- CSR aggregation, L2-striped, x8 unrolled ----------------
template<int RELU>
__global__ __launch_bounds__(64)
void agg_strip(const short* __restrict__ X, short* __restrict__ Y,
               const int* __restrict__ row_off, const int* __restrict__ esrc,
               const float* __restrict__ inv_in, int F)
{
    const int node = blockIdx.y;
    const int c0 = blockIdx.x * 512 + threadIdx.x * 8;
    float acc[8];
    #pragma unroll
    for (int j = 0; j < 8; ++j) acc[j] = 0.f;

    const int beg = row_off[node], end = row_off[node + 1];
    int p = beg;
    for (; p + 7 < end; p += 8) {
        bf8 x[8];
        #pragma unroll
        for (int u = 0; u < 8; ++u)
            x[u] = *reinterpret_cast<const bf8*>(X + (size_t)esrc[p + u] * F + c0);
        #pragma unroll
        for (int u = 0; u < 8; ++u)
            #pragma unroll
            for (int j = 0; j < 8; ++j)
                acc[j] += bf2f((unsigned short)x[u][j]);
    }
    for (; p < end; ++p) {
        bf8 x0 = *reinterpret_cast<const bf8*>(X + (size_t)esrc[p] * F + c0);
        #pragma unroll
        for (int j = 0; j < 8; ++j) acc[j] += bf2f((unsigned short)x0[j]);
    }
    const float sc = inv_in[node];
    bf8 o;
    #pragma unroll
    for (int j = 0; j < 8; ++j) {
        float v = acc[j] * sc;
        if (RELU) v = fmaxf(v, 0.f);
        o[j] = (short)f2bf(v);
    }
    *reinterpret_cast<bf8*>(Y + (size_t)node * F + c0) = o;
}

// ---------------- head-GEMM + softmax (R9) ----------------
__global__ __launch_bounds__(256)
void k_headgemm(const short* __restrict__ H, const float* __restrict__ Wl,
                float* __restrict__ logitsP)
{
    constexpr int RS = 520;
    __shared__ __align__(16) short ldsB[16 * RS];
    const int tid = threadIdx.x;
    const int m0  = blockIdx.x * 256;
    const int k0  = blockIdx.y * 512;
    const int wid = tid >> 6, lane = tid & 63;
    const int fr  = lane & 15;
    const int kq  = lane >> 4;

    {
        const int c = tid & 15, kk = tid >> 4;
        #pragma unroll
        for (int j = 0; j < 32; ++j) {
            const int k = kk * 32 + j;
            ldsB[c * RS + k] = (short)f2bf(Wl[(size_t)(k0 + k) * 16 + c]);
        }
    }
    __syncthreads();

    const int rb0 = m0 + wid * 64;
    f32x4 acc[4];
    #pragma unroll
    for (int mi = 0; mi < 4; ++mi) acc[mi] = (f32x4){0.f, 0.f, 0.f, 0.f};

    #pragma unroll 4
    for (int s = 0; s < 16; ++s) {
        const bf8 b = *reinterpret_cast<const bf8*>(ldsB + fr * RS + s * 32 + kq * 8);
        #pragma unroll
        for (int mi = 0; mi < 4; ++mi) {
            const bf8 a = *reinterpret_cast<const bf8*>(
                H + (size_t)(rb0 + mi * 16 + fr) * 4096 + k0 + s * 32 + kq * 8);
            acc[mi] = __builtin_amdgcn_mfma_f32_16x16x32_bf16(a, b, acc[mi], 0, 0, 0);
        }
    }

    float* outP = logitsP + (size_t)blockIdx.y * 4096 * 16;
    #pragma unroll
    for (int mi = 0; mi < 4; ++mi)
        #pragma unroll
        for (int j = 0; j < 4; ++j)
            outP[(size_t)(rb0 + mi * 16 + kq * 4 + j) * 16 + fr] = acc[mi][j];
}

__global__ __launch_bounds__(64)
void k_soft(const float* __restrict__ logitsP, const float* __restrict__ bl,
            float* __restrict__ out)
{
    const int node = blockIdx.x * 64 + threadIdx.x;
    float l[16];
    #pragma unroll
    for (int c = 0; c < 16; ++c) l[c] = bl[c];
    for (int p = 0; p < 8; ++p) {
        const float4* lp = reinterpret_cast<const float4*>(
            logitsP + ((size_t)p * 4096 + node) * 16);
        #pragma unroll
        for (int q = 0; q < 4; ++q) {
            float4 v = lp[q];
            l[q*4+0] += v.x; l[q*4+1] += v.y; l[q*4+2] += v.z; l[q*4+3] += v.w;
        }
    }
    float mx = l[0];
    #pragma unroll
    for (int c = 1; c < 16; ++c) mx = fmaxf(mx, l[c]);
    float s = 0.f;
    #pragma unroll
    for (int c = 0; c < 16; ++c) { l[c] = expf(l[c] - mx); s += l[c]; }
    const float inv = 1.f / s;
    float4* o = reinterpret_cast<float4*>(out + (size_t)node * 16);
    #pragma unroll
    for (int q = 0; q < 4; ++q)
        o[q] = make_float4(l[q*4+0]*inv, l[q*4+1]*inv, l[q*4+2]*inv, l[q*4+3]*inv);
}

// ---------------- launch ----------------

extern "C" void kernel_launch(void* const* d_in, const int* in_sizes, int n_in,
                              void* d_out, int out_size, void* d_ws, size_t ws_size,
                              hipStream_t stream)
{
    const float* features = (const float*)d_in[0];
    const float* W1       = (const float*)d_in[1];
    const float* b1       = (const float*)d_in[2];
    const float* W2       = (const float*)d_in[3];
    const float* Wl       = (const float*)d_in[4];
    const float* bl       = (const float*)d_in[5];
    const int*   src      = (const int*)d_in[6];
    const int*   dst      = (const int*)d_in[7];
    float* out = (float*)d_out;

    const int N = 4096, IN = 512, H = 8192;
    const int E = in_sizes[6];

    char* ws = (char*)d_ws;
    size_t o = 0;
    auto alloc = [&](size_t bytes) -> char* {
        char* p = ws + o;
        o = (o + bytes + 255) & ~(size_t)255;
        return p;
    };
    short* W2t   = (short*)alloc((size_t)N * H * 2);     // 64 MB  W2^T bf16 [4096][8192]
    short* h1    = (short*)alloc((size_t)N * H * 2);     // 64 MB  conv1 out bf16 [4096][8192]
    short* x2s   = (short*)alloc((size_t)N * N * 2);     // 32 MB  (h1 W2)*inv_out bf16
    short* featb = (short*)alloc((size_t)N * IN * 2);    // 4 MB
    short* aggF  = (short*)alloc((size_t)N * IN * 2);    // 4 MB   A_hat X bf16
    short* W1t   = (short*)alloc((size_t)H * IN * 2);    // 8 MB   W1^T bf16 [8192][512]
    float* logitsP = (float*)alloc((size_t)8 * N * 16 * 4); // 2 MB partial logits
    float* deg_out = (float*)alloc(N * 4);
    float* deg_in  = (float*)alloc(N * 4);
    float* inv_out = (float*)alloc(N * 4);
    float* inv_in  = (float*)alloc(N * 4);
    float* rowsum  = (float*)alloc(N * 4);
    int*   cursor  = (int*)alloc(N * 4);
    int*   row_off = (int*)alloc((N + 1) * 4);
    int*   esrc    = (int*)alloc((size_t)E * 4);
    short* h2 = h1;   // alias: h1 dead after GEMM2, h2 written by agg2

    // graph prep
    k_zero <<<(N + 255) / 256, 256, 0, stream>>>(deg_out, deg_in, cursor, N);
    k_count<<<(E + 255) / 256, 256, 0, stream>>>(src, dst, deg_out, deg_in, E);
    k_inv  <<<(N + 255) / 256, 256, 0, stream>>>(deg_out, deg_in, inv_out, inv_in, N);
    k_scan <<<1, 1024, 0, stream>>>(deg_in, row_off);
    k_fill <<<(E + 255) / 256, 256, 0, stream>>>(src, dst, row_off, cursor, esrc, E);
    k_rowsum<<<N, 64, 0, stream>>>(row_off, esrc, inv_out, inv_in, rowsum);

    // operand conversion
    k_cvt_scale<<<(N * IN / 4 + 255) / 256, 256, 0, stream>>>(features, inv_out, featb,
                                                              N * IN / 4, IN / 4);
    k_tr3<<<dim3(H / 64, IN / 64), 256, 0, stream>>>(W1, W1t, IN, H);
    k_tr3<<<dim3(N / 64, H / 64), 256, 0, stream>>>(W2, W2t, H, N);

    // conv1: aggregate features first (F=512), then GEMM1 with rowsum*b1 epilogue
    agg_strip<0><<<dim3(1, N), 64, 0, stream>>>(featb, aggF, row_off, esrc, inv_in, IN);
    gemm8p<1><<<dim3(H / 128, N / 128), 256, 0, stream>>>(aggF, W1t, h1, b1, rowsum, N, H, IN);

    // conv2: project first, then aggregate (L2-striped: stripe = bid%8 = XCD)
    gemm8p<2><<<dim3(N / 128, N / 128), 256, 0, stream>>>(h1, W2t, x2s, nullptr, inv_out, N, N, H);
    agg_strip<1><<<dim3(N / 512, N), 64, 0, stream>>>(x2s, h2, row_off, esrc, inv_in, N);

    // head: split-K MFMA GEMM -> partials -> reduce+softmax
    k_headgemm<<<dim3(N / 256, 8), 256, 0, stream>>>(h2, Wl, logitsP);
    k_soft<<<N / 64, 64, 0, stream>>>(logitsP, bl, out);
}

// Round 13
// 433.328 us; speedup vs baseline: 1.2329x; 1.2329x over previous
//
#include <hip/hip_runtime.h>
#include <cstdint>
#include <cstddef>

// ---------------------------------------------------------------------------
// GCN forward:  softmax( (A_hat relu(A_hat (X W1 + b1) W2)) Wl + bl )
// conv1 reordered: aggregate features (F=512) first, GEMM1 epilogue adds
// rowsum*b1. conv2: project (8192->4096) then aggregate.
// GEMM: R6/R11 4-phase counted-vmcnt pipeline, 256x256, BK=64, 8 waves,
// 2-buffer LDS with same-buffer region ring, T2 XOR swizzle (0 conflicts),
// T5 setprio, bijective XCD swizzle. Best measured: ~257us, MfmaUtil 47.5%.
// Session landscape (measured): 5 schedule variants at 256^2 all 47+-1%
// (LDS-service+MFMA sum within one barrier domain, ~6% above the structural
// sum-of-pipes bound at 8 waves/CU register-quantum occupancy); 128^2 tile
// = 2 barrier domains but 3.5x fetch -> beyond-L2-bound 310us (worse).
// agg2: 512-col stripes pinned to XCDs via bid%8 -> gather from L2.
// Head: split-K MFMA head-GEMM + reduce/softmax.
// ---------------------------------------------------------------------------

using bf8   = __attribute__((ext_vector_type(8))) short;   // 8 bf16 (4 VGPR)
using s4    = __attribute__((ext_vector_type(4))) short;
using f32x4 = __attribute__((ext_vector_type(4))) float;

static __device__ __forceinline__ unsigned short f2bf(float f) {
    union { float f; uint32_t u; } v; v.f = f;
    uint32_t r = (v.u + 0x7FFFu + ((v.u >> 16) & 1u)) >> 16;   // RNE
    return (unsigned short)r;
}
static __device__ __forceinline__ float bf2f(unsigned short b) {
    union { uint32_t u; float f; } v; v.u = ((uint32_t)b) << 16;
    return v.f;
}

static __device__ __forceinline__ void gload16(const short* g, short* l) {
    __builtin_amdgcn_global_load_lds(
        (const __attribute__((address_space(1))) unsigned int*)g,
        (__attribute__((address_space(3))) unsigned int*)l,
        16, 0, 0);
}

// ---------------- prep kernels ----------------

__global__ void k_zero(float* a, float* b, int* c, int n) {
    int i = blockIdx.x * blockDim.x + threadIdx.x;
    if (i < n) { a[i] = 0.f; b[i] = 0.f; c[i] = 0; }
}

__global__ void k_count(const int* __restrict__ src, const int* __restrict__ dst,
                        float* deg_out, float* deg_in, int E) {
    int e = blockIdx.x * blockDim.x + threadIdx.x;
    if (e < E) {
        atomicAdd(&deg_out[src[e]], 1.f);
        atomicAdd(&deg_in[dst[e]], 1.f);
    }
}

__global__ void k_inv(const float* deg_out, const float* deg_in,
                      float* inv_out, float* inv_in, int n) {
    int i = blockIdx.x * blockDim.x + threadIdx.x;
    if (i < n) {
        inv_out[i] = rsqrtf(fmaxf(deg_out[i], 1.f));
        inv_in[i]  = rsqrtf(fmaxf(deg_in[i], 1.f));
    }
}

__global__ void k_scan(const float* __restrict__ deg_in, int* __restrict__ row_off) {
    __shared__ int part[1024];
    const int t = threadIdx.x;
    int v0 = (int)deg_in[t*4+0], v1 = (int)deg_in[t*4+1],
        v2 = (int)deg_in[t*4+2], v3 = (int)deg_in[t*4+3];
    part[t] = v0 + v1 + v2 + v3;
    __syncthreads();
    for (int off = 1; off < 1024; off <<= 1) {
        int x = (t >= off) ? part[t - off] : 0;
        __syncthreads();
        part[t] += x;
        __syncthreads();
    }
    int run = (t == 0) ? 0 : part[t-1];
    row_off[t*4+0] = run; run += v0;
    row_off[t*4+1] = run; run += v1;
    row_off[t*4+2] = run; run += v2;
    row_off[t*4+3] = run; run += v3;
    if (t == 1023) row_off[4096] = run;
}

__global__ void k_fill(const int* __restrict__ src, const int* __restrict__ dst,
                       const int* __restrict__ row_off, int* cursor,
                       int* __restrict__ esrc, int E) {
    int e = blockIdx.x * blockDim.x + threadIdx.x;
    if (e < E) {
        int d = dst[e];
        int p = atomicAdd(&cursor[d], 1);
        esrc[row_off[d] + p] = src[e];
    }
}

__global__ void k_rowsum(const int* __restrict__ row_off, const int* __restrict__ esrc,
                         const float* __restrict__ inv_out, const float* __restrict__ inv_in,
                         float* __restrict__ rowsum) {
    const int node = blockIdx.x, lane = threadIdx.x;
    const int beg = row_off[node], end = row_off[node + 1];
    float s = 0.f;
    for (int p = beg + lane; p < end; p += 64) s += inv_out[esrc[p]];
    #pragma unroll
    for (int off = 32; off; off >>= 1) s += __shfl_down(s, off, 64);
    if (lane == 0) rowsum[node] = s * inv_in[node];
}

__global__ void k_cvt_scale(const float* __restrict__ in, const float* __restrict__ sc,
                            short* __restrict__ out, int n4, int f4) {
    int i = blockIdx.x * blockDim.x + threadIdx.x;
    if (i < n4) {
        const float s = sc[i / f4];
        float4 v = reinterpret_cast<const float4*>(in)[i];
        s4 o;
        o[0] = (short)f2bf(v.x * s); o[1] = (short)f2bf(v.y * s);
        o[2] = (short)f2bf(v.z * s); o[3] = (short)f2bf(v.w * s);
        reinterpret_cast<s4*>(out)[i] = o;
    }
}

// fp32 [R][C] -> bf16 [C][R]; 64x64 tiles, 256 threads.
__global__ __launch_bounds__(256)
void k_tr3(const float* __restrict__ in, short* __restrict__ out, int R, int C) {
    __shared__ float tile[64][65];
    const int bc = blockIdx.x * 64, br = blockIdx.y * 64;
    const int t = threadIdx.x;
    const int rr = t >> 4, cq = (t & 15) * 4;
    #pragma unroll
    for (int p = 0; p < 4; ++p) {
        const int r = rr + p * 16;
        float4 v = *reinterpret_cast<const float4*>(&in[(size_t)(br + r) * C + bc + cq]);
        tile[r][cq + 0] = v.x; tile[r][cq + 1] = v.y;
        tile[r][cq + 2] = v.z; tile[r][cq + 3] = v.w;
    }
    __syncthreads();
    const int cc = t >> 4, rq = (t & 15) * 4;
    #pragma unroll
    for (int p = 0; p < 4; ++p) {
        const int c = cc + p * 16;
        s4 o;
        o[0] = (short)f2bf(tile[rq + 0][c]);
        o[1] = (short)f2bf(tile[rq + 1][c]);
        o[2] = (short)f2bf(tile[rq + 2][c]);
        o[3] = (short)f2bf(tile[rq + 3][c]);
        *reinterpret_cast<s4*>(&out[(size_t)(bc + c) * R + br + rq]) = o;
    }
}

// ---------------- bf16 MFMA GEMM, 4-phase counted-vmcnt pipeline ----------------
template<int EPI>
__global__ __launch_bounds__(512, 2)
void gemm8p(const short* __restrict__ A, const short* __restrict__ Bt,
            short* __restrict__ C,
            const float* __restrict__ bias, const float* __restrict__ rs,
            int M, int N, int K)
{
    constexpr int USZ  = 4096;            // shorts per 64-row x 64-short unit
    constexpr int BOFF = 4 * USZ;         // B region offset within buffer (16384)
    constexpr int BUF  = 8 * USZ;         // shorts per buffer (32768 = 64KB)
    __shared__ __align__(16) short lds[2 * BUF];   // 128 KB
    const int tid  = threadIdx.x;
    const int wid  = tid >> 6, lane = tid & 63;
    const int wm   = wid >> 2;            // 0..1  (M wave index)
    const int wn   = wid & 3;             // 0..3  (N wave index)
    const int fr   = lane & 15;
    const int kq   = lane >> 4;           // 0..3
    const int nt   = K >> 6;

    // bijective XCD-chunk swizzle (nwg % 8 == 0)
    const int gx  = gridDim.x;
    const int nwg = gx * gridDim.y;
    int bid = blockIdx.y * gx + blockIdx.x;
    bid = (bid & 7) * (nwg >> 3) + (bid >> 3);
    const int tm = (bid / gx) * 256;
    const int tn = (bid % gx) * 256;

    // ---- staging addressing ----
    const int srow = tid >> 3;
    const int scq  = tid & 7;
    const int scs  = scq ^ (srow & 7);    // pre-swizzled source chunk
    const short* gA = A  + (size_t)(tm + srow) * K + scs * 8;
    const short* gB = Bt + (size_t)(tn + srow) * K + scs * 8;
    short* const ldst = lds + tid * 8;

    // ---- fragment read offsets ----
    const int cx0 = (0 * 4 + kq) ^ (fr & 7);
    const int cx1 = (1 * 4 + kq) ^ (fr & 7);
    int aoff[8][2], boff[4][2];
    #pragma unroll
    for (int mi = 0; mi < 8; ++mi) {
        const int r = wm * 128 + mi * 16 + fr;
        aoff[mi][0] = r * 64 + cx0 * 8;
        aoff[mi][1] = r * 64 + cx1 * 8;
    }
    #pragma unroll
    for (int n = 0; n < 4; ++n) {
        const int r = wn * 64 + n * 16 + fr;
        boff[n][0] = BOFF + r * 64 + cx0 * 8;
        boff[n][1] = BOFF + r * 64 + cx1 * 8;
    }

    f32x4 acc[8][4];
    #pragma unroll
    for (int mi = 0; mi < 8; ++mi)
        #pragma unroll
        for (int n = 0; n < 4; ++n)
            acc[mi][n] = (f32x4){0.f, 0.f, 0.f, 0.f};

    // ---- prologue: stage tile 0 -> buf0, tile 1 -> buf1; wait tile 0 ----
    #pragma unroll
    for (int u = 0; u < 4; ++u) gload16(gA + (size_t)u * 64 * K, ldst + u * USZ);
    #pragma unroll
    for (int v = 0; v < 4; ++v) gload16(gB + (size_t)v * 64 * K, ldst + BOFF + v * USZ);
    #pragma unroll
    for (int u = 0; u < 4; ++u) gload16(gA + (size_t)u * 64 * K + 64, ldst + BUF + u * USZ);
    #pragma unroll
    for (int v = 0; v < 4; ++v) gload16(gB + (size_t)v * 64 * K + 64, ldst + BUF + BOFF + v * USZ);
    asm volatile("s_waitcnt vmcnt(8)" ::: "memory");
    __builtin_amdgcn_sched_barrier(0);
    __builtin_amdgcn_s_barrier();

    for (int t = 0; t < nt; ++t) {
        const int cc = (t & 1) * BUF;
        const bool pf = (t + 2 < nt);
        const size_t kf = (size_t)(t + 2) * 64;

        bf8 a03[4][2], a47[4][2], bg[4][2];

        // ---- P0: read A m0-3 (8) + B n0-1 (4); 16 MFMA (m0-3 x n0-1) ----
        #pragma unroll
        for (int mi = 0; mi < 4; ++mi)
            #pragma unroll
            for (int s = 0; s < 2; ++s)
                a03[mi][s] = *reinterpret_cast<const bf8*>(lds + cc + aoff[mi][s]);
        #pragma unroll
        for (int n = 0; n < 2; ++n)
            #pragma unroll
            for (int s = 0; s < 2; ++s)
                bg[n][s] = *reinterpret_cast<const bf8*>(lds + cc + boff[n][s]);
        __builtin_amdgcn_s_barrier();
        asm volatile("s_waitcnt lgkmcnt(0)" ::: "memory");
        __builtin_amdgcn_s_setprio(1);
        #pragma unroll
        for (int mi = 0; mi < 4; ++mi)
            #pragma unroll
            for (int n = 0; n < 2; ++n)
                #pragma unroll
                for (int s = 0; s < 2; ++s)
                    acc[mi][n] = __builtin_amdgcn_mfma_f32_16x16x32_bf16(a03[mi][s], bg[n][s], acc[mi][n], 0, 0, 0);
        __builtin_amdgcn_s_setprio(0);
        __builtin_amdgcn_s_barrier();

        // ---- P1: read B n2-3 (4); 16 MFMA (m0-3 x n2-3) ----
        #pragma unroll
        for (int n = 2; n < 4; ++n)
            #pragma unroll
            for (int s = 0; s < 2; ++s)
                bg[n][s] = *reinterpret_cast<const bf8*>(lds + cc + boff[n][s]);
        __builtin_amdgcn_s_barrier();
        asm volatile("s_waitcnt lgkmcnt(0)" ::: "memory");
        __builtin_amdgcn_s_setprio(1);
        #pragma unroll
        for (int mi = 0; mi < 4; ++mi)
            #pragma unroll
            for (int n = 2; n < 4; ++n)
                #pragma unroll
                for (int s = 0; s < 2; ++s)
                    acc[mi][n] = __builtin_amdgcn_mfma_f32_16x16x32_bf16(a03[mi][s], bg[n][s], acc[mi][n], 0, 0, 0);
        __builtin_amdgcn_s_setprio(0);
        __builtin_amdgcn_s_barrier();
        // B region of tile t dead (frags reg-cached, reads drained) => overwritable.

        // ---- P2: read A m4-7 (8); stage B(t+2) into cc; 16 MFMA (m4-7 x n0-1) ----
        #pragma unroll
        for (int mi = 0; mi < 4; ++mi)
            #pragma unroll
            for (int s = 0; s < 2; ++s)
                a47[mi][s] = *reinterpret_cast<const bf8*>(lds + cc + aoff[4 + mi][s]);
        if (pf) {
            #pragma unroll
            for (int v = 0; v < 4; ++v)
                gload16(gB + (size_t)v * 64 * K + kf, ldst + cc + BOFF + v * USZ);
        }
        __builtin_amdgcn_s_barrier();
        asm volatile("s_waitcnt lgkmcnt(0)" ::: "memory");
        __builtin_amdgcn_s_setprio(1);
        #pragma unroll
        for (int mi = 0; mi < 4; ++mi)
            #pragma unroll
            for (int n = 0; n < 2; ++n)
                #pragma unroll
                for (int s = 0; s < 2; ++s)
                    acc[4 + mi][n] = __builtin_amdgcn_mfma_f32_16x16x32_bf16(a47[mi][s], bg[n][s], acc[4 + mi][n], 0, 0, 0);
        __builtin_amdgcn_s_setprio(0);
        __builtin_amdgcn_s_barrier();
        // A region of tile t dead => overwritable.

        // ---- P3: stage A(t+2) into cc; 16 MFMA (m4-7 x n2-3); counted wait ----
        if (pf) {
            #pragma unroll
            for (int u = 0; u < 4; ++u)
                gload16(gA + (size_t)u * 64 * K + kf, ldst + cc + u * USZ);
        }
        __builtin_amdgcn_s_setprio(1);
        #pragma unroll
        for (int mi = 0; mi < 4; ++mi)
            #pragma unroll
            for (int n = 2; n < 4; ++n)
                #pragma unroll
                for (int s = 0; s < 2; ++s)
                    acc[4 + mi][n] = __builtin_amdgcn_mfma_f32_16x16x32_bf16(a47[mi][s], bg[n][s], acc[4 + mi][n], 0, 0, 0);
        __builtin_amdgcn_s_setprio(0);
        if (pf) {
            asm volatile("s_waitcnt vmcnt(8)" ::: "memory");   // t+1 landed; t+2 in flight
        } else if (t + 2 == nt) {
            asm volatile("s_waitcnt vmcnt(0)" ::: "memory");   // last prefetched tile
        }
        __builtin_amdgcn_s_barrier();
    }

    // ---- epilogue: C/D layout col = lane&15, row = (lane>>4)*4 + reg ----
    const int rb = kq * 4;
    #pragma unroll
    for (int mi = 0; mi < 8; ++mi) {
        #pragma unroll
        for (int n = 0; n < 4; ++n) {
            const int col = tn + wn * 64 + n * 16 + fr;
            const float bcol = (EPI == 1) ? bias[col] : 0.f;
            #pragma unroll
            for (int j = 0; j < 4; ++j) {
                const int row = tm + wm * 128 + mi * 16 + rb + j;
                float v = acc[mi][n][j];
                if (EPI == 1) v += rs[row] * bcol;
                else          v *= rs[row];
                C[(size_t)row * N + col] = (short)f2bf(v);
            }
        }
    }
}

// ---------------- CSR aggregation, L2-striped, x8 unrolled ----------------
template<int RELU>
__global__ __launch_bounds__(64)
void agg_strip(const short* __restrict__ X, short* __restrict__ Y,
               const int* __restrict__ row_off, const int* __restrict__ esrc,
               const float* __restrict__ inv_in, int F)
{
    const int node = blockIdx.y;
    const int c0 = blockIdx.x * 512 + threadIdx.x * 8;
    float acc[8];
    #pragma unroll
    for (int j = 0; j < 8; ++j) acc[j] = 0.f;

    const int beg = row_off[node], end = row_off[node + 1];
    int p = beg;
    for (; p + 7 < end; p += 8) {
        bf8 x[8];
        #pragma unroll
        for (int u = 0; u < 8; ++u)
            x[u] = *reinterpret_cast<const bf8*>(X + (size_t)esrc[p + u] * F + c0);
        #pragma unroll
        for (int u = 0; u < 8; ++u)
            #pragma unroll
            for (int j = 0; j < 8; ++j)
                acc[j] += bf2f((unsigned short)x[u][j]);
    }
    for (; p < end; ++p) {
        bf8 x0 = *reinterpret_cast<const bf8*>(X + (size_t)esrc[p] * F + c0);
        #pragma unroll
        for (int j = 0; j < 8; ++j) acc[j] += bf2f((unsigned short)x0[j]);
    }
    const float sc = inv_in[node];
    bf8 o;
    #pragma unroll
    for (int j = 0; j < 8; ++j) {
        float v = acc[j] * sc;
        if (RELU) v = fmaxf(v, 0.f);
        o[j] = (short)f2bf(v);
    }
    *reinterpret_cast<bf8*>(Y + (size_t)node * F + c0) = o;
}

// ---------------- head-GEMM + softmax ----------------
__global__ __launch_bounds__(256)
void k_headgemm(const short* __restrict__ H, const float* __restrict__ Wl,
                float* __restrict__ logitsP)
{
    constexpr int RS = 520;
    __shared__ __align__(16) short ldsB[16 * RS];
    const int tid = threadIdx.x;
    const int m0  = blockIdx.x * 256;
    const int k0  = blockIdx.y * 512;
    const int wid = tid >> 6, lane = tid & 63;
    const int fr  = lane & 15;
    const int kq  = lane >> 4;

    {
        const int c = tid & 15, kk = tid >> 4;
        #pragma unroll
        for (int j = 0; j < 32; ++j) {
            const int k = kk * 32 + j;
            ldsB[c * RS + k] = (short)f2bf(Wl[(size_t)(k0 + k) * 16 + c]);
        }
    }
    __syncthreads();

    const int rb0 = m0 + wid * 64;
    f32x4 acc[4];
    #pragma unroll
    for (int mi = 0; mi < 4; ++mi) acc[mi] = (f32x4){0.f, 0.f, 0.f, 0.f};

    #pragma unroll 4
    for (int s = 0; s < 16; ++s) {
        const bf8 b = *reinterpret_cast<const bf8*>(ldsB + fr * RS + s * 32 + kq * 8);
        #pragma unroll
        for (int mi = 0; mi < 4; ++mi) {
            const bf8 a = *reinterpret_cast<const bf8*>(
                H + (size_t)(rb0 + mi * 16 + fr) * 4096 + k0 + s * 32 + kq * 8);
            acc[mi] = __builtin_amdgcn_mfma_f32_16x16x32_bf16(a, b, acc[mi], 0, 0, 0);
        }
    }

    float* outP = logitsP + (size_t)blockIdx.y * 4096 * 16;
    #pragma unroll
    for (int mi = 0; mi < 4; ++mi)
        #pragma unroll
        for (int j = 0; j < 4; ++j)
            outP[(size_t)(rb0 + mi * 16 + kq * 4 + j) * 16 + fr] = acc[mi][j];
}

__global__ __launch_bounds__(64)
void k_soft(const float* __restrict__ logitsP, const float* __restrict__ bl,
            float* __restrict__ out)
{
    const int node = blockIdx.x * 64 + threadIdx.x;
    float l[16];
    #pragma unroll
    for (int c = 0; c < 16; ++c) l[c] = bl[c];
    for (int p = 0; p < 8; ++p) {
        const float4* lp = reinterpret_cast<const float4*>(
            logitsP + ((size_t)p * 4096 + node) * 16);
        #pragma unroll
        for (int q = 0; q < 4; ++q) {
            float4 v = lp[q];
            l[q*4+0] += v.x; l[q*4+1] += v.y; l[q*4+2] += v.z; l[q*4+3] += v.w;
        }
    }
    float mx = l[0];
    #pragma unroll
    for (int c = 1; c < 16; ++c) mx = fmaxf(mx, l[c]);
    float s = 0.f;
    #pragma unroll
    for (int c = 0; c < 16; ++c) { l[c] = expf(l[c] - mx); s += l[c]; }
    const float inv = 1.f / s;
    float4* o = reinterpret_cast<float4*>(out + (size_t)node * 16);
    #pragma unroll
    for (int q = 0; q < 4; ++q)
        o[q] = make_float4(l[q*4+0]*inv, l[q*4+1]*inv, l[q*4+2]*inv, l[q*4+3]*inv);
}

// ---------------- launch ----------------

extern "C" void kernel_launch(void* const* d_in, const int* in_sizes, int n_in,
                              void* d_out, int out_size, void* d_ws, size_t ws_size,
                              hipStream_t stream)
{
    const float* features = (const float*)d_in[0];
    const float* W1       = (const float*)d_in[1];
    const float* b1       = (const float*)d_in[2];
    const float* W2       = (const float*)d_in[3];
    const float* Wl       = (const float*)d_in[4];
    const float* bl       = (const float*)d_in[5];
    const int*   src      = (const int*)d_in[6];
    const int*   dst      = (const int*)d_in[7];
    float* out = (float*)d_out;

    const int N = 4096, IN = 512, H = 8192;
    const int E = in_sizes[6];

    char* ws = (char*)d_ws;
    size_t o = 0;
    auto alloc = [&](size_t bytes) -> char* {
        char* p = ws + o;
        o = (o + bytes + 255) & ~(size_t)255;
        return p;
    };
    short* W2t   = (short*)alloc((size_t)N * H * 2);     // 64 MB  W2^T bf16 [4096][8192]
    short* h1    = (short*)alloc((size_t)N * H * 2);     // 64 MB  conv1 out bf16 [4096][8192]
    short* x2s   = (short*)alloc((size_t)N * N * 2);     // 32 MB  (h1 W2)*inv_out bf16
    short* featb = (short*)alloc((size_t)N * IN * 2);    // 4 MB
    short* aggF  = (short*)alloc((size_t)N * IN * 2);    // 4 MB   A_hat X bf16
    short* W1t   = (short*)alloc((size_t)H * IN * 2);    // 8 MB   W1^T bf16 [8192][512]
    float* logitsP = (float*)alloc((size_t)8 * N * 16 * 4); // 2 MB partial logits
    float* deg_out = (float*)alloc(N * 4);
    float* deg_in  = (float*)alloc(N * 4);
    float* inv_out = (float*)alloc(N * 4);
    float* inv_in  = (float*)alloc(N * 4);
    float* rowsum  = (float*)alloc(N * 4);
    int*   cursor  = (int*)alloc(N * 4);
    int*   row_off = (int*)alloc((N + 1) * 4);
    int*   esrc    = (int*)alloc((size_t)E * 4);
    short* h2 = h1;   // alias: h1 dead after GEMM2, h2 written by agg2

    // graph prep
    k_zero <<<(N + 255) / 256, 256, 0, stream>>>(deg_out, deg_in, cursor, N);
    k_count<<<(E + 255) / 256, 256, 0, stream>>>(src, dst, deg_out, deg_in, E);
    k_inv  <<<(N + 255) / 256, 256, 0, stream>>>(deg_out, deg_in, inv_out, inv_in, N);
    k_scan <<<1, 1024, 0, stream>>>(deg_in, row_off);
    k_fill <<<(E + 255) / 256, 256, 0, stream>>>(src, dst, row_off, cursor, esrc, E);
    k_rowsum<<<N, 64, 0, stream>>>(row_off, esrc, inv_out, inv_in, rowsum);

    // operand conversion
    k_cvt_scale<<<(N * IN / 4 + 255) / 256, 256, 0, stream>>>(features, inv_out, featb,
                                                              N * IN / 4, IN / 4);
    k_tr3<<<dim3(H / 64, IN / 64), 256, 0, stream>>>(W1, W1t, IN, H);
    k_tr3<<<dim3(N / 64, H / 64), 256, 0, stream>>>(W2, W2t, H, N);

    // conv1: aggregate features first (F=512), then GEMM1 with rowsum*b1 epilogue
    agg_strip<0><<<dim3(1, N), 64, 0, stream>>>(featb, aggF, row_off, esrc, inv_in, IN);
    gemm8p<1><<<dim3(H / 256, N / 256), 512, 0, stream>>>(aggF, W1t, h1, b1, rowsum, N, H, IN);

    // conv2: project first, then aggregate (L2-striped: stripe = bid%8 = XCD)
    gemm8p<2><<<dim3(N / 256, N / 256), 512, 0, stream>>>(h1, W2t, x2s, nullptr, inv_out, N, N, H);
    agg_strip<1><<<dim3(N / 512, N), 64, 0, stream>>>(x2s, h2, row_off, esrc, inv_in, N);

    // head: split-K MFMA GEMM -> partials -> reduce+softmax
    k_headgemm<<<dim3(N / 256, 8), 256, 0, stream>>>(h2, Wl, logitsP);
    k_soft<<<N / 64, 64, 0, stream>>>(logitsP, bl, out);
}